// Round 4
// baseline (411.786 us; speedup 1.0000x reference)
//
#include <hip/hip_runtime.h>

typedef __attribute__((ext_vector_type(8))) short bf16x8;
typedef __attribute__((ext_vector_type(4))) float f32x4;

#define SCALE_F 0.17677669529663687f
#define LOG2E_F 1.4426950408889634f

__device__ __forceinline__ unsigned short f2bf(float f) {
    union { float f; unsigned int u; } v; v.f = f;
    unsigned int r = v.u + 0x7FFFu + ((v.u >> 16) & 1u);
    return (unsigned short)(r >> 16);
}

__device__ __forceinline__ unsigned pack2(float lo, float hi) {
    return (unsigned)f2bf(lo) | ((unsigned)f2bf(hi) << 16);
}

// Linear XOR swizzle (row bits folded into 16B-block bits) — keeps b128 reads
// and uint2 stores balanced across banks. Bijective within each row.
__device__ __forceinline__ int swzm(int row) {
    return ((row & 1) << 4)
         ^ ((((row >> 1) ^ (row >> 2)) & 1) << 5)
         ^ ((((row >> 2) ^ (row >> 3)) & 1) << 6);
}
__device__ __forceinline__ int swzA(int row, int col) {   // 512-B rows
    return (((row << 9) + (col << 1)) ^ swzm(row));
}
__device__ __forceinline__ int swzB(int row, int col) {   // 128-B rows
    return (((row << 7) + (col << 1)) ^ swzm(row));
}

// ---------------- prep kernels ----------------
extern "C" __global__ void prep_gbs_k(const float* __restrict__ emb,
                                      const float* __restrict__ pw,
                                      float* __restrict__ gbs) {
    int i = blockIdx.x * 256 + threadIdx.x;      // 8*768
    if (i >= 8 * 768) return;
    int b = i / 768, o = i - b * 768;
    const float* e = emb + b * 512;
    const float* wr = pw + o * 512;
    float s = 0.f;
    for (int k = 0; k < 512; k += 4) {
        float4 ev = *(const float4*)(e + k);
        float4 wv = *(const float4*)(wr + k);
        s += ev.x * wv.x + ev.y * wv.y + ev.z * wv.z + ev.w * wv.w;
    }
    gbs[i] = s;
}

extern "C" __global__ void prep_w_k(const float* __restrict__ wq, const float* __restrict__ wk,
                                    const float* __restrict__ wv, const float* __restrict__ wo,
                                    unsigned short* __restrict__ dst) {
    int i = blockIdx.x * 256 + threadIdx.x;      // 65536 float4-quads total
    int sel = i >> 14;
    const float* s = (sel == 0) ? wq : (sel == 1) ? wk : (sel == 2) ? wv : wo;
    float4 v = *(const float4*)(s + (i & 16383) * 4);
    ushort4 p;
    p.x = f2bf(v.x); p.y = f2bf(v.y); p.z = f2bf(v.z); p.w = f2bf(v.w);
    *(ushort4*)(dst + i * 4) = p;
}

extern "C" __global__ void prep_bias_k(const float* __restrict__ bt, float* __restrict__ bp) {
    int i = blockIdx.x * 256 + threadIdx.x;      // 8*64*64  [h][i][j]
    int h = i >> 12, r = (i >> 6) & 63, cc = i & 63;
    float v;
    if (cc >= 49) v = -1e30f;                    // mask pad key columns
    else if (r >= 49) v = 0.f;                   // dead query rows
    else {
        int ri = r / 7, ci = r - ri * 7, rj = cc / 7, cj = cc - rj * 7;
        int rel = (ri - rj + 6) * 13 + (ci - cj + 6);
        v = bt[rel * 8 + h];
    }
    bp[i] = v;
}

// ---------------- main fused kernel ----------------
// grid 2048, 512 threads (8 waves, wave w = head w). 76.8 KiB LDS -> 2 blocks/CU.
//   [0,25600)      xm  bf16 [50][256]  -> attn-out after bar3
//   [25600,51200)  q   bf16 [50][256]  \__ after bar2: v^T bf16 [256][64] at 25600
//   [51200,76800)  k   bf16 [50][256]  /
extern "C" __global__ void __launch_bounds__(512, 4)
attn_main(const float* __restrict__ x,
          const float* __restrict__ lnw, const float* __restrict__ lnb,
          const unsigned short* __restrict__ wqb, const unsigned short* __restrict__ wkb,
          const unsigned short* __restrict__ wvb, const unsigned short* __restrict__ wob,
          const float* __restrict__ gbs, const float* __restrict__ bpad,
          float* __restrict__ out)
{
    __shared__ char lds[76800];
    const int tid = threadIdx.x;
    const int w = tid >> 6;          // wave == head
    const int l = tid & 63;
    const int g = l >> 4;
    const int c = l & 15;
    const int win = blockIdx.x;
    const int bb = win >> 8;
    const int QR = 25600, KR = 51200, VT = 25600;
    const f32x4 z4 = {0.f, 0.f, 0.f, 0.f};
    const bf16x8 z8 = {0, 0, 0, 0, 0, 0, 0, 0};

    // ---- AdaLayerNorm -> xm rows 0..48 (+ zero row 49) ----
    {
        float4 lnw4 = *(const float4*)(lnw + 4 * l);
        float4 lnb4 = *(const float4*)(lnb + 4 * l);
        float4 gam4 = *(const float4*)(gbs + bb * 768 + 4 * l);
        float4 bet4 = *(const float4*)(gbs + bb * 768 + 256 + 4 * l);
        for (int t = w; t < 49; t += 8) {
            float4 v = *(const float4*)(x + ((size_t)win * 49 + t) * 256 + 4 * l);
            float s = v.x + v.y + v.z + v.w;
            float ss = v.x * v.x + v.y * v.y + v.z * v.z + v.w * v.w;
            #pragma unroll
            for (int off = 32; off >= 1; off >>= 1) {
                s += __shfl_xor(s, off);
                ss += __shfl_xor(ss, off);
            }
            float mu = s * (1.0f / 256.0f);
            float var = ss * (1.0f / 256.0f) - mu * mu;
            float rstd = rsqrtf(var + 1e-5f);
            ushort4 p;
            p.x = f2bf(((v.x - mu) * rstd * lnw4.x + lnb4.x) * (1.0f + gam4.x) + bet4.x);
            p.y = f2bf(((v.y - mu) * rstd * lnw4.y + lnb4.y) * (1.0f + gam4.y) + bet4.y);
            p.z = f2bf(((v.z - mu) * rstd * lnw4.z + lnb4.z) * (1.0f + gam4.z) + bet4.z);
            p.w = f2bf(((v.w - mu) * rstd * lnw4.w + lnb4.w) * (1.0f + gam4.w) + bet4.w);
            *(ushort4*)(lds + swzA(t, 4 * l)) = p;
        }
        if (w == 7) {
            ushort4 zp; zp.x = 0; zp.y = 0; zp.z = 0; zp.w = 0;
            *(ushort4*)(lds + swzA(49, 4 * l)) = zp;
        }
    }
    __syncthreads();     // bar1: xm ready

    // ---- Q/K projections (swapped: A=W rows=d, B=xm rows=tok) ----
    #pragma unroll
    for (int p = 0; p < 2; ++p) {
        const unsigned short* W = p ? wkb : wqb;
        const int base = p ? KR : QR;
        f32x4 acc[2][4];
        #pragma unroll
        for (int dt = 0; dt < 2; ++dt)
            #pragma unroll
            for (int tt = 0; tt < 4; ++tt) acc[dt][tt] = z4;
        #pragma unroll
        for (int kt = 0; kt < 8; ++kt) {
            const int ko = kt * 32 + g * 8;
            bf16x8 b0 = *(const bf16x8*)(lds + swzA(c, ko));
            bf16x8 b1 = *(const bf16x8*)(lds + swzA(16 + c, ko));
            bf16x8 b2 = *(const bf16x8*)(lds + swzA(32 + c, ko));
            bf16x8 b3 = z8; if (c < 2) b3 = *(const bf16x8*)(lds + swzA(48 + c, ko));
            bf16x8 a0 = *(const bf16x8*)(W + (w * 32 + c) * 256 + ko);
            bf16x8 a1 = *(const bf16x8*)(W + (w * 32 + 16 + c) * 256 + ko);
            acc[0][0] = __builtin_amdgcn_mfma_f32_16x16x32_bf16(a0, b0, acc[0][0], 0, 0, 0);
            acc[0][1] = __builtin_amdgcn_mfma_f32_16x16x32_bf16(a0, b1, acc[0][1], 0, 0, 0);
            acc[0][2] = __builtin_amdgcn_mfma_f32_16x16x32_bf16(a0, b2, acc[0][2], 0, 0, 0);
            acc[0][3] = __builtin_amdgcn_mfma_f32_16x16x32_bf16(a0, b3, acc[0][3], 0, 0, 0);
            acc[1][0] = __builtin_amdgcn_mfma_f32_16x16x32_bf16(a1, b0, acc[1][0], 0, 0, 0);
            acc[1][1] = __builtin_amdgcn_mfma_f32_16x16x32_bf16(a1, b1, acc[1][1], 0, 0, 0);
            acc[1][2] = __builtin_amdgcn_mfma_f32_16x16x32_bf16(a1, b2, acc[1][2], 0, 0, 0);
            acc[1][3] = __builtin_amdgcn_mfma_f32_16x16x32_bf16(a1, b3, acc[1][3], 0, 0, 0);
        }
        // store Q/K[tok][d] with contiguous d-quads (uint2)
        #pragma unroll
        for (int dt = 0; dt < 2; ++dt)
            #pragma unroll
            for (int tt = 0; tt < 4; ++tt)
                if (tt < 3 || c < 2) {
                    uint2 u;
                    u.x = pack2(acc[dt][tt][0], acc[dt][tt][1]);
                    u.y = pack2(acc[dt][tt][2], acc[dt][tt][3]);
                    *(uint2*)(lds + base + swzA(tt * 16 + c, w * 32 + dt * 16 + 4 * g)) = u;
                }
    }

    // ---- QK^T (swapped: sim^T, row i on lane-c) + softmax + in-reg P pack ----
    unsigned pk[4][4][2];   // [jt][it][half]
    {
        const int hd = w * 32 + g * 8;
        bf16x8 kf0 = *(const bf16x8*)(lds + KR + swzA(c, hd));
        bf16x8 kf1 = *(const bf16x8*)(lds + KR + swzA(16 + c, hd));
        bf16x8 kf2 = *(const bf16x8*)(lds + KR + swzA(32 + c, hd));
        bf16x8 kf3 = z8; if (c < 2) kf3 = *(const bf16x8*)(lds + KR + swzA(48 + c, hd));
        #pragma unroll
        for (int it = 0; it < 4; ++it) {
            bf16x8 qf = z8;
            if (it < 3 || c < 2) qf = *(const bf16x8*)(lds + QR + swzA(it * 16 + c, hd));
            f32x4 s0 = __builtin_amdgcn_mfma_f32_16x16x32_bf16(kf0, qf, z4, 0, 0, 0);
            f32x4 s1 = __builtin_amdgcn_mfma_f32_16x16x32_bf16(kf1, qf, z4, 0, 0, 0);
            f32x4 s2 = __builtin_amdgcn_mfma_f32_16x16x32_bf16(kf2, qf, z4, 0, 0, 0);
            f32x4 s3 = __builtin_amdgcn_mfma_f32_16x16x32_bf16(kf3, qf, z4, 0, 0, 0);
            const float* bp = bpad + w * 4096 + (it * 16 + c) * 64 + 4 * g;
            float4 B0 = *(const float4*)(bp);
            float4 B1 = *(const float4*)(bp + 16);
            float4 B2 = *(const float4*)(bp + 32);
            float4 B3 = *(const float4*)(bp + 48);
            s0[0] = s0[0] * SCALE_F + B0.x; s0[1] = s0[1] * SCALE_F + B0.y;
            s0[2] = s0[2] * SCALE_F + B0.z; s0[3] = s0[3] * SCALE_F + B0.w;
            s1[0] = s1[0] * SCALE_F + B1.x; s1[1] = s1[1] * SCALE_F + B1.y;
            s1[2] = s1[2] * SCALE_F + B1.z; s1[3] = s1[3] * SCALE_F + B1.w;
            s2[0] = s2[0] * SCALE_F + B2.x; s2[1] = s2[1] * SCALE_F + B2.y;
            s2[2] = s2[2] * SCALE_F + B2.z; s2[3] = s2[3] * SCALE_F + B2.w;
            s3[0] = s3[0] * SCALE_F + B3.x; s3[1] = s3[1] * SCALE_F + B3.y;
            s3[2] = s3[2] * SCALE_F + B3.z; s3[3] = s3[3] * SCALE_F + B3.w;
            float mm = fmaxf(fmaxf(fmaxf(s0[0], s0[1]), fmaxf(s0[2], s0[3])),
                       fmaxf(fmaxf(fmaxf(s1[0], s1[1]), fmaxf(s1[2], s1[3])),
                       fmaxf(fmaxf(fmaxf(s2[0], s2[1]), fmaxf(s2[2], s2[3])),
                             fmaxf(fmaxf(s3[0], s3[1]), fmaxf(s3[2], s3[3])))));
            mm = fmaxf(mm, __shfl_xor(mm, 16));
            mm = fmaxf(mm, __shfl_xor(mm, 32));
            #pragma unroll
            for (int r = 0; r < 4; ++r) {
                s0[r] = exp2f((s0[r] - mm) * LOG2E_F);
                s1[r] = exp2f((s1[r] - mm) * LOG2E_F);
                s2[r] = exp2f((s2[r] - mm) * LOG2E_F);
                s3[r] = exp2f((s3[r] - mm) * LOG2E_F);
            }
            float ss = (s0[0] + s0[1] + s0[2] + s0[3]) + (s1[0] + s1[1] + s1[2] + s1[3])
                     + (s2[0] + s2[1] + s2[2] + s2[3]) + (s3[0] + s3[1] + s3[2] + s3[3]);
            ss += __shfl_xor(ss, 16);
            ss += __shfl_xor(ss, 32);
            float iv = 1.0f / ss;
            #pragma unroll
            for (int r = 0; r < 4; ++r) { s0[r] *= iv; s1[r] *= iv; s2[r] *= iv; s3[r] *= iv; }
            pk[0][it][0] = pack2(s0[0], s0[1]); pk[0][it][1] = pack2(s0[2], s0[3]);
            pk[1][it][0] = pack2(s1[0], s1[1]); pk[1][it][1] = pack2(s1[2], s1[3]);
            pk[2][it][0] = pack2(s2[0], s2[1]); pk[2][it][1] = pack2(s2[2], s2[3]);
            pk[3][it][0] = pack2(s3[0], s3[1]); pk[3][it][1] = pack2(s3[2], s3[3]);
        }
    }
    // ---- in-register P redistribution -> PV B-fragments ----
    bf16x8 pv[4][2];
    {
        const int srcA = ((l >> 4) & 1) * 32 + (l & 15);
        const int srcB = srcA + 16;
        const bool hiSel = (l >= 32);
        #pragma unroll
        for (int kt = 0; kt < 2; ++kt)
            #pragma unroll
            for (int it = 0; it < 4; ++it) {
                unsigned u0, u1, u2, u3;
                {
                    unsigned x0 = (unsigned)__shfl((int)pk[2 * kt][it][0], srcA);
                    unsigned x1 = (unsigned)__shfl((int)pk[2 * kt + 1][it][0], srcA);
                    u0 = hiSel ? x1 : x0;
                }
                {
                    unsigned x0 = (unsigned)__shfl((int)pk[2 * kt][it][1], srcA);
                    unsigned x1 = (unsigned)__shfl((int)pk[2 * kt + 1][it][1], srcA);
                    u1 = hiSel ? x1 : x0;
                }
                {
                    unsigned x0 = (unsigned)__shfl((int)pk[2 * kt][it][0], srcB);
                    unsigned x1 = (unsigned)__shfl((int)pk[2 * kt + 1][it][0], srcB);
                    u2 = hiSel ? x1 : x0;
                }
                {
                    unsigned x0 = (unsigned)__shfl((int)pk[2 * kt][it][1], srcB);
                    unsigned x1 = (unsigned)__shfl((int)pk[2 * kt + 1][it][1], srcB);
                    u3 = hiSel ? x1 : x0;
                }
                bf16x8 vv;
                vv[0] = (short)(u0 & 0xffffu); vv[1] = (short)(u0 >> 16);
                vv[2] = (short)(u1 & 0xffffu); vv[3] = (short)(u1 >> 16);
                vv[4] = (short)(u2 & 0xffffu); vv[5] = (short)(u2 >> 16);
                vv[6] = (short)(u3 & 0xffffu); vv[7] = (short)(u3 >> 16);
                pv[it][kt] = vv;
            }
    }
    __syncthreads();     // bar2: Q/K regions dead -> v^T may overwrite

    // ---- V projection (unswapped) -> v^T[256][64] ----
    {
        f32x4 acc[2][4];   // [cti][tt]
        #pragma unroll
        for (int cti = 0; cti < 2; ++cti)
            #pragma unroll
            for (int tt = 0; tt < 4; ++tt) acc[cti][tt] = z4;
        #pragma unroll
        for (int kt = 0; kt < 8; ++kt) {
            const int ko = kt * 32 + g * 8;
            bf16x8 a0 = *(const bf16x8*)(lds + swzA(c, ko));
            bf16x8 a1 = *(const bf16x8*)(lds + swzA(16 + c, ko));
            bf16x8 a2 = *(const bf16x8*)(lds + swzA(32 + c, ko));
            bf16x8 a3 = z8; if (c < 2) a3 = *(const bf16x8*)(lds + swzA(48 + c, ko));
            bf16x8 b0 = *(const bf16x8*)(wvb + (w * 32 + c) * 256 + ko);
            bf16x8 b1 = *(const bf16x8*)(wvb + (w * 32 + 16 + c) * 256 + ko);
            acc[0][0] = __builtin_amdgcn_mfma_f32_16x16x32_bf16(a0, b0, acc[0][0], 0, 0, 0);
            acc[0][1] = __builtin_amdgcn_mfma_f32_16x16x32_bf16(a1, b0, acc[0][1], 0, 0, 0);
            acc[0][2] = __builtin_amdgcn_mfma_f32_16x16x32_bf16(a2, b0, acc[0][2], 0, 0, 0);
            acc[0][3] = __builtin_amdgcn_mfma_f32_16x16x32_bf16(a3, b0, acc[0][3], 0, 0, 0);
            acc[1][0] = __builtin_amdgcn_mfma_f32_16x16x32_bf16(a0, b1, acc[1][0], 0, 0, 0);
            acc[1][1] = __builtin_amdgcn_mfma_f32_16x16x32_bf16(a1, b1, acc[1][1], 0, 0, 0);
            acc[1][2] = __builtin_amdgcn_mfma_f32_16x16x32_bf16(a2, b1, acc[1][2], 0, 0, 0);
            acc[1][3] = __builtin_amdgcn_mfma_f32_16x16x32_bf16(a3, b1, acc[1][3], 0, 0, 0);
        }
        #pragma unroll
        for (int cti = 0; cti < 2; ++cti)
            #pragma unroll
            for (int tt = 0; tt < 4; ++tt) {
                uint2 u;
                u.x = pack2(acc[cti][tt][0], acc[cti][tt][1]);
                u.y = pack2(acc[cti][tt][2], acc[cti][tt][3]);
                *(uint2*)(lds + VT + swzB(w * 32 + cti * 16 + c, tt * 16 + 4 * g)) = u;
            }
    }
    __syncthreads();     // bar3: all xm reads done; v^T ready

    // ---- PV (A=v^T rows=d, B=in-reg P) -> attn-out[tok][d] into xm region ----
    {
        f32x4 o[2][4];   // [dt][it]
        #pragma unroll
        for (int dt = 0; dt < 2; ++dt)
            #pragma unroll
            for (int it = 0; it < 4; ++it) o[dt][it] = z4;
        #pragma unroll
        for (int kt = 0; kt < 2; ++kt) {
            const int ko = kt * 32 + g * 8;
            bf16x8 va0 = *(const bf16x8*)(lds + VT + swzB(w * 32 + c, ko));
            bf16x8 va1 = *(const bf16x8*)(lds + VT + swzB(w * 32 + 16 + c, ko));
            #pragma unroll
            for (int it = 0; it < 4; ++it) {
                o[0][it] = __builtin_amdgcn_mfma_f32_16x16x32_bf16(va0, pv[it][kt], o[0][it], 0, 0, 0);
                o[1][it] = __builtin_amdgcn_mfma_f32_16x16x32_bf16(va1, pv[it][kt], o[1][it], 0, 0, 0);
            }
        }
        #pragma unroll
        for (int dt = 0; dt < 2; ++dt)
            #pragma unroll
            for (int it = 0; it < 4; ++it)
                if (it < 3 || c < 2) {
                    uint2 u;
                    u.x = pack2(o[dt][it][0], o[dt][it][1]);
                    u.y = pack2(o[dt][it][2], o[dt][it][3]);
                    *(uint2*)(lds + swzA(it * 16 + c, w * 32 + dt * 16 + 4 * g)) = u;
                }
    }
    __syncthreads();     // bar4: attn-out ready

    // ---- O projection (swapped) + sigma gate -> float4 global stores ----
    {
        f32x4 acc[2][4];
        #pragma unroll
        for (int dt = 0; dt < 2; ++dt)
            #pragma unroll
            for (int tt = 0; tt < 4; ++tt) acc[dt][tt] = z4;
        #pragma unroll
        for (int kt = 0; kt < 8; ++kt) {
            const int ko = kt * 32 + g * 8;
            bf16x8 b0 = *(const bf16x8*)(lds + swzA(c, ko));
            bf16x8 b1 = *(const bf16x8*)(lds + swzA(16 + c, ko));
            bf16x8 b2 = *(const bf16x8*)(lds + swzA(32 + c, ko));
            bf16x8 b3 = z8; if (c < 2) b3 = *(const bf16x8*)(lds + swzA(48 + c, ko));
            bf16x8 a0 = *(const bf16x8*)(wob + (w * 32 + c) * 256 + ko);
            bf16x8 a1 = *(const bf16x8*)(wob + (w * 32 + 16 + c) * 256 + ko);
            acc[0][0] = __builtin_amdgcn_mfma_f32_16x16x32_bf16(a0, b0, acc[0][0], 0, 0, 0);
            acc[0][1] = __builtin_amdgcn_mfma_f32_16x16x32_bf16(a0, b1, acc[0][1], 0, 0, 0);
            acc[0][2] = __builtin_amdgcn_mfma_f32_16x16x32_bf16(a0, b2, acc[0][2], 0, 0, 0);
            acc[0][3] = __builtin_amdgcn_mfma_f32_16x16x32_bf16(a0, b3, acc[0][3], 0, 0, 0);
            acc[1][0] = __builtin_amdgcn_mfma_f32_16x16x32_bf16(a1, b0, acc[1][0], 0, 0, 0);
            acc[1][1] = __builtin_amdgcn_mfma_f32_16x16x32_bf16(a1, b1, acc[1][1], 0, 0, 0);
            acc[1][2] = __builtin_amdgcn_mfma_f32_16x16x32_bf16(a1, b2, acc[1][2], 0, 0, 0);
            acc[1][3] = __builtin_amdgcn_mfma_f32_16x16x32_bf16(a1, b3, acc[1][3], 0, 0, 0);
        }
        #pragma unroll
        for (int dt = 0; dt < 2; ++dt) {
            const int col = w * 32 + dt * 16 + 4 * g;
            float4 sg = *(const float4*)(gbs + bb * 768 + 512 + col);
            #pragma unroll
            for (int tt = 0; tt < 4; ++tt) {
                int tok = tt * 16 + c;
                if (tok < 49) {
                    float4 o4;
                    o4.x = acc[dt][tt][0] * sg.x;
                    o4.y = acc[dt][tt][1] * sg.y;
                    o4.z = acc[dt][tt][2] * sg.z;
                    o4.w = acc[dt][tt][3] * sg.w;
                    *(float4*)(out + ((size_t)win * 49 + tok) * 256 + col) = o4;
                }
            }
        }
    }
}

extern "C" void kernel_launch(void* const* d_in, const int* in_sizes, int n_in,
                              void* d_out, int out_size, void* d_ws, size_t ws_size,
                              hipStream_t stream) {
    (void)in_sizes; (void)n_in; (void)out_size; (void)ws_size;
    const float* x   = (const float*)d_in[0];
    const float* emb = (const float*)d_in[1];
    const float* lnw = (const float*)d_in[2];
    const float* lnb = (const float*)d_in[3];
    const float* pw  = (const float*)d_in[4];
    const float* wq  = (const float*)d_in[5];
    const float* wk  = (const float*)d_in[6];
    const float* wv  = (const float*)d_in[7];
    const float* wo  = (const float*)d_in[8];
    const float* bt  = (const float*)d_in[9];
    float* out = (float*)d_out;

    char* ws = (char*)d_ws;
    float* gbs = (float*)ws;                                   // 24576 B
    unsigned short* wb = (unsigned short*)(ws + 24576);        // 524288 B
    float* biasp = (float*)(ws + 24576 + 524288);              // 131072 B

    prep_gbs_k<<<24, 256, 0, stream>>>(emb, pw, gbs);
    prep_w_k<<<256, 256, 0, stream>>>(wq, wk, wv, wo, wb);
    prep_bias_k<<<128, 256, 0, stream>>>(bt, biasp);
    attn_main<<<2048, 512, 0, stream>>>(x, lnw, lnb,
                                        wb, wb + 65536, wb + 131072, wb + 196608,
                                        gbs, biasp, out);
}

// Round 5
// 246.799 us; speedup vs baseline: 1.6685x; 1.6685x over previous
//
#include <hip/hip_runtime.h>

typedef __attribute__((ext_vector_type(8))) short bf16x8;
typedef __attribute__((ext_vector_type(4))) float f32x4;

#define SCALE_F 0.17677669529663687f
#define LOG2E_F 1.4426950408889634f

__device__ __forceinline__ unsigned short f2bf(float f) {
    union { float f; unsigned int u; } v; v.f = f;
    unsigned int r = v.u + 0x7FFFu + ((v.u >> 16) & 1u);
    return (unsigned short)(r >> 16);
}

__device__ __forceinline__ unsigned pack2(float lo, float hi) {
    return (unsigned)f2bf(lo) | ((unsigned)f2bf(hi) << 16);
}

// Linear XOR swizzle (row bits folded into 16B-block bits) — keeps b128 reads
// and uint2 stores balanced across banks. Bijective within each row.
__device__ __forceinline__ int swzm(int row) {
    return ((row & 1) << 4)
         ^ ((((row >> 1) ^ (row >> 2)) & 1) << 5)
         ^ ((((row >> 2) ^ (row >> 3)) & 1) << 6);
}
__device__ __forceinline__ int swzA(int row, int col) {   // 512-B rows
    return (((row << 9) + (col << 1)) ^ swzm(row));
}
__device__ __forceinline__ int swzB(int row, int col) {   // 128-B rows
    return (((row << 7) + (col << 1)) ^ swzm(row));
}

// ---------------- prep kernels ----------------
extern "C" __global__ void prep_gbs_k(const float* __restrict__ emb,
                                      const float* __restrict__ pw,
                                      float* __restrict__ gbs) {
    int i = blockIdx.x * 256 + threadIdx.x;      // 8*768
    if (i >= 8 * 768) return;
    int b = i / 768, o = i - b * 768;
    const float* e = emb + b * 512;
    const float* wr = pw + o * 512;
    float s = 0.f;
    for (int k = 0; k < 512; k += 4) {
        float4 ev = *(const float4*)(e + k);
        float4 wv = *(const float4*)(wr + k);
        s += ev.x * wv.x + ev.y * wv.y + ev.z * wv.z + ev.w * wv.w;
    }
    gbs[i] = s;
}

extern "C" __global__ void prep_w_k(const float* __restrict__ wq, const float* __restrict__ wk,
                                    const float* __restrict__ wv, const float* __restrict__ wo,
                                    unsigned short* __restrict__ dst) {
    int i = blockIdx.x * 256 + threadIdx.x;      // 65536 float4-quads total
    int sel = i >> 14;
    const float* s = (sel == 0) ? wq : (sel == 1) ? wk : (sel == 2) ? wv : wo;
    float4 v = *(const float4*)(s + (i & 16383) * 4);
    ushort4 p;
    p.x = f2bf(v.x); p.y = f2bf(v.y); p.z = f2bf(v.z); p.w = f2bf(v.w);
    *(ushort4*)(dst + i * 4) = p;
}

extern "C" __global__ void prep_bias_k(const float* __restrict__ bt, float* __restrict__ bp) {
    int i = blockIdx.x * 256 + threadIdx.x;      // 8*64*64  [h][i][j]
    int h = i >> 12, r = (i >> 6) & 63, cc = i & 63;
    float v;
    if (cc >= 49) v = -1e30f;                    // mask pad key columns
    else if (r >= 49) v = 0.f;                   // dead query rows
    else {
        int ri = r / 7, ci = r - ri * 7, rj = cc / 7, cj = cc - rj * 7;
        int rel = (ri - rj + 6) * 13 + (ci - cj + 6);
        v = bt[rel * 8 + h];
    }
    bp[i] = v;
}

// ---------------- main fused kernel ----------------
// grid 2048, 512 threads (8 waves, wave w = head w). 76.8 KiB LDS -> 2 blocks/CU.
// NOTE: __launch_bounds__ arg2 empirically acts as min BLOCKS/CU on this hipcc
// ((512,4) -> 64-VGPR cap -> catastrophic spill, r4). (512,2) -> 128-VGPR cap.
//   [0,25600)      xm  bf16 [50][256]  -> attn-out after bar3
//   [25600,51200)  q   bf16 [50][256]  \__ after bar2: v^T bf16 [256][64] at 25600
//   [51200,76800)  k   bf16 [50][256]  /
extern "C" __global__ void __launch_bounds__(512, 2)
attn_main(const float* __restrict__ x,
          const float* __restrict__ lnw, const float* __restrict__ lnb,
          const unsigned short* __restrict__ wqb, const unsigned short* __restrict__ wkb,
          const unsigned short* __restrict__ wvb, const unsigned short* __restrict__ wob,
          const float* __restrict__ gbs, const float* __restrict__ bpad,
          float* __restrict__ out)
{
    __shared__ char lds[76800];
    const int tid = threadIdx.x;
    const int w = tid >> 6;          // wave == head
    const int l = tid & 63;
    const int g = l >> 4;
    const int c = l & 15;
    const int win = blockIdx.x;
    const int bb = win >> 8;
    const int QR = 25600, KR = 51200, VT = 25600;
    const f32x4 z4 = {0.f, 0.f, 0.f, 0.f};
    const bf16x8 z8 = {0, 0, 0, 0, 0, 0, 0, 0};

    // ---- AdaLayerNorm -> xm rows 0..48 (+ zero row 49) ----
    {
        float4 lnw4 = *(const float4*)(lnw + 4 * l);
        float4 lnb4 = *(const float4*)(lnb + 4 * l);
        float4 gam4 = *(const float4*)(gbs + bb * 768 + 4 * l);
        float4 bet4 = *(const float4*)(gbs + bb * 768 + 256 + 4 * l);
        for (int t = w; t < 49; t += 8) {
            float4 v = *(const float4*)(x + ((size_t)win * 49 + t) * 256 + 4 * l);
            float s = v.x + v.y + v.z + v.w;
            float ss = v.x * v.x + v.y * v.y + v.z * v.z + v.w * v.w;
            #pragma unroll
            for (int off = 32; off >= 1; off >>= 1) {
                s += __shfl_xor(s, off);
                ss += __shfl_xor(ss, off);
            }
            float mu = s * (1.0f / 256.0f);
            float var = ss * (1.0f / 256.0f) - mu * mu;
            float rstd = rsqrtf(var + 1e-5f);
            ushort4 p;
            p.x = f2bf(((v.x - mu) * rstd * lnw4.x + lnb4.x) * (1.0f + gam4.x) + bet4.x);
            p.y = f2bf(((v.y - mu) * rstd * lnw4.y + lnb4.y) * (1.0f + gam4.y) + bet4.y);
            p.z = f2bf(((v.z - mu) * rstd * lnw4.z + lnb4.z) * (1.0f + gam4.z) + bet4.z);
            p.w = f2bf(((v.w - mu) * rstd * lnw4.w + lnb4.w) * (1.0f + gam4.w) + bet4.w);
            *(ushort4*)(lds + swzA(t, 4 * l)) = p;
        }
        if (w == 7) {
            ushort4 zp; zp.x = 0; zp.y = 0; zp.z = 0; zp.w = 0;
            *(ushort4*)(lds + swzA(49, 4 * l)) = zp;
        }
    }
    __syncthreads();     // bar1: xm ready

    // ---- Q/K projections (swapped: A=W rows=d, B=xm rows=tok) ----
    #pragma unroll
    for (int p = 0; p < 2; ++p) {
        const unsigned short* W = p ? wkb : wqb;
        const int base = p ? KR : QR;
        f32x4 acc[2][4];
        #pragma unroll
        for (int dt = 0; dt < 2; ++dt)
            #pragma unroll
            for (int tt = 0; tt < 4; ++tt) acc[dt][tt] = z4;
        #pragma unroll
        for (int kt = 0; kt < 8; ++kt) {
            const int ko = kt * 32 + g * 8;
            bf16x8 b0 = *(const bf16x8*)(lds + swzA(c, ko));
            bf16x8 b1 = *(const bf16x8*)(lds + swzA(16 + c, ko));
            bf16x8 b2 = *(const bf16x8*)(lds + swzA(32 + c, ko));
            bf16x8 b3 = z8; if (c < 2) b3 = *(const bf16x8*)(lds + swzA(48 + c, ko));
            bf16x8 a0 = *(const bf16x8*)(W + (w * 32 + c) * 256 + ko);
            bf16x8 a1 = *(const bf16x8*)(W + (w * 32 + 16 + c) * 256 + ko);
            acc[0][0] = __builtin_amdgcn_mfma_f32_16x16x32_bf16(a0, b0, acc[0][0], 0, 0, 0);
            acc[0][1] = __builtin_amdgcn_mfma_f32_16x16x32_bf16(a0, b1, acc[0][1], 0, 0, 0);
            acc[0][2] = __builtin_amdgcn_mfma_f32_16x16x32_bf16(a0, b2, acc[0][2], 0, 0, 0);
            acc[0][3] = __builtin_amdgcn_mfma_f32_16x16x32_bf16(a0, b3, acc[0][3], 0, 0, 0);
            acc[1][0] = __builtin_amdgcn_mfma_f32_16x16x32_bf16(a1, b0, acc[1][0], 0, 0, 0);
            acc[1][1] = __builtin_amdgcn_mfma_f32_16x16x32_bf16(a1, b1, acc[1][1], 0, 0, 0);
            acc[1][2] = __builtin_amdgcn_mfma_f32_16x16x32_bf16(a1, b2, acc[1][2], 0, 0, 0);
            acc[1][3] = __builtin_amdgcn_mfma_f32_16x16x32_bf16(a1, b3, acc[1][3], 0, 0, 0);
        }
        // store Q/K[tok][d] with contiguous d-quads (uint2)
        #pragma unroll
        for (int dt = 0; dt < 2; ++dt)
            #pragma unroll
            for (int tt = 0; tt < 4; ++tt)
                if (tt < 3 || c < 2) {
                    uint2 u;
                    u.x = pack2(acc[dt][tt][0], acc[dt][tt][1]);
                    u.y = pack2(acc[dt][tt][2], acc[dt][tt][3]);
                    *(uint2*)(lds + base + swzA(tt * 16 + c, w * 32 + dt * 16 + 4 * g)) = u;
                }
    }

    // ---- QK^T (swapped: sim^T, row i on lane-c) + softmax + fused in-reg
    //      P redistribution (pk is an 8-reg temp per it-tile; pv accumulates) ----
    bf16x8 pv[4][2];
    {
        const int srcA = ((l >> 4) & 1) * 32 + (l & 15);
        const int srcB = srcA + 16;
        const bool hiSel = (l >= 32);
        const int hd = w * 32 + g * 8;
        bf16x8 kf0 = *(const bf16x8*)(lds + KR + swzA(c, hd));
        bf16x8 kf1 = *(const bf16x8*)(lds + KR + swzA(16 + c, hd));
        bf16x8 kf2 = *(const bf16x8*)(lds + KR + swzA(32 + c, hd));
        bf16x8 kf3 = z8; if (c < 2) kf3 = *(const bf16x8*)(lds + KR + swzA(48 + c, hd));
        #pragma unroll
        for (int it = 0; it < 4; ++it) {
            bf16x8 qf = z8;
            if (it < 3 || c < 2) qf = *(const bf16x8*)(lds + QR + swzA(it * 16 + c, hd));
            f32x4 s0 = __builtin_amdgcn_mfma_f32_16x16x32_bf16(kf0, qf, z4, 0, 0, 0);
            f32x4 s1 = __builtin_amdgcn_mfma_f32_16x16x32_bf16(kf1, qf, z4, 0, 0, 0);
            f32x4 s2 = __builtin_amdgcn_mfma_f32_16x16x32_bf16(kf2, qf, z4, 0, 0, 0);
            f32x4 s3 = __builtin_amdgcn_mfma_f32_16x16x32_bf16(kf3, qf, z4, 0, 0, 0);
            const float* bp = bpad + w * 4096 + (it * 16 + c) * 64 + 4 * g;
            float4 B0 = *(const float4*)(bp);
            float4 B1 = *(const float4*)(bp + 16);
            float4 B2 = *(const float4*)(bp + 32);
            float4 B3 = *(const float4*)(bp + 48);
            s0[0] = s0[0] * SCALE_F + B0.x; s0[1] = s0[1] * SCALE_F + B0.y;
            s0[2] = s0[2] * SCALE_F + B0.z; s0[3] = s0[3] * SCALE_F + B0.w;
            s1[0] = s1[0] * SCALE_F + B1.x; s1[1] = s1[1] * SCALE_F + B1.y;
            s1[2] = s1[2] * SCALE_F + B1.z; s1[3] = s1[3] * SCALE_F + B1.w;
            s2[0] = s2[0] * SCALE_F + B2.x; s2[1] = s2[1] * SCALE_F + B2.y;
            s2[2] = s2[2] * SCALE_F + B2.z; s2[3] = s2[3] * SCALE_F + B2.w;
            s3[0] = s3[0] * SCALE_F + B3.x; s3[1] = s3[1] * SCALE_F + B3.y;
            s3[2] = s3[2] * SCALE_F + B3.z; s3[3] = s3[3] * SCALE_F + B3.w;
            float mm = fmaxf(fmaxf(fmaxf(s0[0], s0[1]), fmaxf(s0[2], s0[3])),
                       fmaxf(fmaxf(fmaxf(s1[0], s1[1]), fmaxf(s1[2], s1[3])),
                       fmaxf(fmaxf(fmaxf(s2[0], s2[1]), fmaxf(s2[2], s2[3])),
                             fmaxf(fmaxf(s3[0], s3[1]), fmaxf(s3[2], s3[3])))));
            mm = fmaxf(mm, __shfl_xor(mm, 16));
            mm = fmaxf(mm, __shfl_xor(mm, 32));
            #pragma unroll
            for (int r = 0; r < 4; ++r) {
                s0[r] = exp2f((s0[r] - mm) * LOG2E_F);
                s1[r] = exp2f((s1[r] - mm) * LOG2E_F);
                s2[r] = exp2f((s2[r] - mm) * LOG2E_F);
                s3[r] = exp2f((s3[r] - mm) * LOG2E_F);
            }
            float ss = (s0[0] + s0[1] + s0[2] + s0[3]) + (s1[0] + s1[1] + s1[2] + s1[3])
                     + (s2[0] + s2[1] + s2[2] + s2[3]) + (s3[0] + s3[1] + s3[2] + s3[3]);
            ss += __shfl_xor(ss, 16);
            ss += __shfl_xor(ss, 32);
            float iv = 1.0f / ss;
            #pragma unroll
            for (int r = 0; r < 4; ++r) { s0[r] *= iv; s1[r] *= iv; s2[r] *= iv; s3[r] *= iv; }
            unsigned pkt[4][2];
            pkt[0][0] = pack2(s0[0], s0[1]); pkt[0][1] = pack2(s0[2], s0[3]);
            pkt[1][0] = pack2(s1[0], s1[1]); pkt[1][1] = pack2(s1[2], s1[3]);
            pkt[2][0] = pack2(s2[0], s2[1]); pkt[2][1] = pack2(s2[2], s2[3]);
            pkt[3][0] = pack2(s3[0], s3[1]); pkt[3][1] = pack2(s3[2], s3[3]);
            // fused redistribution: build this it-tile's PV B-fragments now
            #pragma unroll
            for (int kt = 0; kt < 2; ++kt) {
                unsigned u0, u1, u2, u3;
                {
                    unsigned x0 = (unsigned)__shfl((int)pkt[2 * kt][0], srcA);
                    unsigned x1 = (unsigned)__shfl((int)pkt[2 * kt + 1][0], srcA);
                    u0 = hiSel ? x1 : x0;
                }
                {
                    unsigned x0 = (unsigned)__shfl((int)pkt[2 * kt][1], srcA);
                    unsigned x1 = (unsigned)__shfl((int)pkt[2 * kt + 1][1], srcA);
                    u1 = hiSel ? x1 : x0;
                }
                {
                    unsigned x0 = (unsigned)__shfl((int)pkt[2 * kt][0], srcB);
                    unsigned x1 = (unsigned)__shfl((int)pkt[2 * kt + 1][0], srcB);
                    u2 = hiSel ? x1 : x0;
                }
                {
                    unsigned x0 = (unsigned)__shfl((int)pkt[2 * kt][1], srcB);
                    unsigned x1 = (unsigned)__shfl((int)pkt[2 * kt + 1][1], srcB);
                    u3 = hiSel ? x1 : x0;
                }
                bf16x8 vv;
                vv[0] = (short)(u0 & 0xffffu); vv[1] = (short)(u0 >> 16);
                vv[2] = (short)(u1 & 0xffffu); vv[3] = (short)(u1 >> 16);
                vv[4] = (short)(u2 & 0xffffu); vv[5] = (short)(u2 >> 16);
                vv[6] = (short)(u3 & 0xffffu); vv[7] = (short)(u3 >> 16);
                pv[it][kt] = vv;
            }
        }
    }
    __syncthreads();     // bar2: Q/K regions dead -> v^T may overwrite

    // ---- V projection (unswapped) -> v^T[256][64] ----
    {
        f32x4 acc[2][4];   // [cti][tt]
        #pragma unroll
        for (int cti = 0; cti < 2; ++cti)
            #pragma unroll
            for (int tt = 0; tt < 4; ++tt) acc[cti][tt] = z4;
        #pragma unroll
        for (int kt = 0; kt < 8; ++kt) {
            const int ko = kt * 32 + g * 8;
            bf16x8 a0 = *(const bf16x8*)(lds + swzA(c, ko));
            bf16x8 a1 = *(const bf16x8*)(lds + swzA(16 + c, ko));
            bf16x8 a2 = *(const bf16x8*)(lds + swzA(32 + c, ko));
            bf16x8 a3 = z8; if (c < 2) a3 = *(const bf16x8*)(lds + swzA(48 + c, ko));
            bf16x8 b0 = *(const bf16x8*)(wvb + (w * 32 + c) * 256 + ko);
            bf16x8 b1 = *(const bf16x8*)(wvb + (w * 32 + 16 + c) * 256 + ko);
            acc[0][0] = __builtin_amdgcn_mfma_f32_16x16x32_bf16(a0, b0, acc[0][0], 0, 0, 0);
            acc[0][1] = __builtin_amdgcn_mfma_f32_16x16x32_bf16(a1, b0, acc[0][1], 0, 0, 0);
            acc[0][2] = __builtin_amdgcn_mfma_f32_16x16x32_bf16(a2, b0, acc[0][2], 0, 0, 0);
            acc[0][3] = __builtin_amdgcn_mfma_f32_16x16x32_bf16(a3, b0, acc[0][3], 0, 0, 0);
            acc[1][0] = __builtin_amdgcn_mfma_f32_16x16x32_bf16(a0, b1, acc[1][0], 0, 0, 0);
            acc[1][1] = __builtin_amdgcn_mfma_f32_16x16x32_bf16(a1, b1, acc[1][1], 0, 0, 0);
            acc[1][2] = __builtin_amdgcn_mfma_f32_16x16x32_bf16(a2, b1, acc[1][2], 0, 0, 0);
            acc[1][3] = __builtin_amdgcn_mfma_f32_16x16x32_bf16(a3, b1, acc[1][3], 0, 0, 0);
        }
        #pragma unroll
        for (int cti = 0; cti < 2; ++cti)
            #pragma unroll
            for (int tt = 0; tt < 4; ++tt) {
                uint2 u;
                u.x = pack2(acc[cti][tt][0], acc[cti][tt][1]);
                u.y = pack2(acc[cti][tt][2], acc[cti][tt][3]);
                *(uint2*)(lds + VT + swzB(w * 32 + cti * 16 + c, tt * 16 + 4 * g)) = u;
            }
    }
    __syncthreads();     // bar3: all xm reads done; v^T ready

    // ---- PV (A=v^T rows=d, B=in-reg P) -> attn-out[tok][d] into xm region ----
    {
        f32x4 o[2][4];   // [dt][it]
        #pragma unroll
        for (int dt = 0; dt < 2; ++dt)
            #pragma unroll
            for (int it = 0; it < 4; ++it) o[dt][it] = z4;
        #pragma unroll
        for (int kt = 0; kt < 2; ++kt) {
            const int ko = kt * 32 + g * 8;
            bf16x8 va0 = *(const bf16x8*)(lds + VT + swzB(w * 32 + c, ko));
            bf16x8 va1 = *(const bf16x8*)(lds + VT + swzB(w * 32 + 16 + c, ko));
            #pragma unroll
            for (int it = 0; it < 4; ++it) {
                o[0][it] = __builtin_amdgcn_mfma_f32_16x16x32_bf16(va0, pv[it][kt], o[0][it], 0, 0, 0);
                o[1][it] = __builtin_amdgcn_mfma_f32_16x16x32_bf16(va1, pv[it][kt], o[1][it], 0, 0, 0);
            }
        }
        #pragma unroll
        for (int dt = 0; dt < 2; ++dt)
            #pragma unroll
            for (int it = 0; it < 4; ++it)
                if (it < 3 || c < 2) {
                    uint2 u;
                    u.x = pack2(o[dt][it][0], o[dt][it][1]);
                    u.y = pack2(o[dt][it][2], o[dt][it][3]);
                    *(uint2*)(lds + swzA(it * 16 + c, w * 32 + dt * 16 + 4 * g)) = u;
                }
    }
    __syncthreads();     // bar4: attn-out ready

    // ---- O projection (swapped) + sigma gate -> float4 global stores ----
    {
        f32x4 acc[2][4];
        #pragma unroll
        for (int dt = 0; dt < 2; ++dt)
            #pragma unroll
            for (int tt = 0; tt < 4; ++tt) acc[dt][tt] = z4;
        #pragma unroll
        for (int kt = 0; kt < 8; ++kt) {
            const int ko = kt * 32 + g * 8;
            bf16x8 b0 = *(const bf16x8*)(lds + swzA(c, ko));
            bf16x8 b1 = *(const bf16x8*)(lds + swzA(16 + c, ko));
            bf16x8 b2 = *(const bf16x8*)(lds + swzA(32 + c, ko));
            bf16x8 b3 = z8; if (c < 2) b3 = *(const bf16x8*)(lds + swzA(48 + c, ko));
            bf16x8 a0 = *(const bf16x8*)(wob + (w * 32 + c) * 256 + ko);
            bf16x8 a1 = *(const bf16x8*)(wob + (w * 32 + 16 + c) * 256 + ko);
            acc[0][0] = __builtin_amdgcn_mfma_f32_16x16x32_bf16(a0, b0, acc[0][0], 0, 0, 0);
            acc[0][1] = __builtin_amdgcn_mfma_f32_16x16x32_bf16(a0, b1, acc[0][1], 0, 0, 0);
            acc[0][2] = __builtin_amdgcn_mfma_f32_16x16x32_bf16(a0, b2, acc[0][2], 0, 0, 0);
            acc[0][3] = __builtin_amdgcn_mfma_f32_16x16x32_bf16(a0, b3, acc[0][3], 0, 0, 0);
            acc[1][0] = __builtin_amdgcn_mfma_f32_16x16x32_bf16(a1, b0, acc[1][0], 0, 0, 0);
            acc[1][1] = __builtin_amdgcn_mfma_f32_16x16x32_bf16(a1, b1, acc[1][1], 0, 0, 0);
            acc[1][2] = __builtin_amdgcn_mfma_f32_16x16x32_bf16(a1, b2, acc[1][2], 0, 0, 0);
            acc[1][3] = __builtin_amdgcn_mfma_f32_16x16x32_bf16(a1, b3, acc[1][3], 0, 0, 0);
        }
        #pragma unroll
        for (int dt = 0; dt < 2; ++dt) {
            const int col = w * 32 + dt * 16 + 4 * g;
            float4 sg = *(const float4*)(gbs + bb * 768 + 512 + col);
            #pragma unroll
            for (int tt = 0; tt < 4; ++tt) {
                int tok = tt * 16 + c;
                if (tok < 49) {
                    float4 o4;
                    o4.x = acc[dt][tt][0] * sg.x;
                    o4.y = acc[dt][tt][1] * sg.y;
                    o4.z = acc[dt][tt][2] * sg.z;
                    o4.w = acc[dt][tt][3] * sg.w;
                    *(float4*)(out + ((size_t)win * 49 + tok) * 256 + col) = o4;
                }
            }
        }
    }
}

extern "C" void kernel_launch(void* const* d_in, const int* in_sizes, int n_in,
                              void* d_out, int out_size, void* d_ws, size_t ws_size,
                              hipStream_t stream) {
    (void)in_sizes; (void)n_in; (void)out_size; (void)ws_size;
    const float* x   = (const float*)d_in[0];
    const float* emb = (const float*)d_in[1];
    const float* lnw = (const float*)d_in[2];
    const float* lnb = (const float*)d_in[3];
    const float* pw  = (const float*)d_in[4];
    const float* wq  = (const float*)d_in[5];
    const float* wk  = (const float*)d_in[6];
    const float* wv  = (const float*)d_in[7];
    const float* wo  = (const float*)d_in[8];
    const float* bt  = (const float*)d_in[9];
    float* out = (float*)d_out;

    char* ws = (char*)d_ws;
    float* gbs = (float*)ws;                                   // 24576 B
    unsigned short* wb = (unsigned short*)(ws + 24576);        // 524288 B
    float* biasp = (float*)(ws + 24576 + 524288);              // 131072 B

    prep_gbs_k<<<24, 256, 0, stream>>>(emb, pw, gbs);
    prep_w_k<<<256, 256, 0, stream>>>(wq, wk, wv, wo, wb);
    prep_bias_k<<<128, 256, 0, stream>>>(bt, biasp);
    attn_main<<<2048, 512, 0, stream>>>(x, lnw, lnb,
                                        wb, wb + 65536, wb + 131072, wb + 196608,
                                        gbs, biasp, out);
}

// Round 6
// 242.442 us; speedup vs baseline: 1.6985x; 1.0180x over previous
//
#include <hip/hip_runtime.h>

typedef __attribute__((ext_vector_type(8))) short bf16x8;
typedef __attribute__((ext_vector_type(4))) float f32x4;

#define SCALE_F 0.17677669529663687f
#define LOG2E_F 1.4426950408889634f

__device__ __forceinline__ unsigned short f2bf(float f) {
    union { float f; unsigned int u; } v; v.f = f;
    unsigned int r = v.u + 0x7FFFu + ((v.u >> 16) & 1u);
    return (unsigned short)(r >> 16);
}

__device__ __forceinline__ unsigned pack2(float lo, float hi) {
    return (unsigned)f2bf(lo) | ((unsigned)f2bf(hi) << 16);
}

__device__ __forceinline__ bf16x8 build8(unsigned u0, unsigned u1, unsigned u2, unsigned u3) {
    bf16x8 vv;
    vv[0] = (short)(u0 & 0xffffu); vv[1] = (short)(u0 >> 16);
    vv[2] = (short)(u1 & 0xffffu); vv[3] = (short)(u1 >> 16);
    vv[4] = (short)(u2 & 0xffffu); vv[5] = (short)(u2 >> 16);
    vv[6] = (short)(u3 & 0xffffu); vv[7] = (short)(u3 >> 16);
    return vv;
}

// Linear XOR swizzle (row bits folded into 16B-block bits).
__device__ __forceinline__ int swzm(int row) {
    return ((row & 1) << 4)
         ^ ((((row >> 1) ^ (row >> 2)) & 1) << 5)
         ^ ((((row >> 2) ^ (row >> 3)) & 1) << 6);
}
__device__ __forceinline__ int swzA(int row, int col) {   // 512-B rows
    return (((row << 9) + (col << 1)) ^ swzm(row));
}

// ---------------- prep kernels ----------------
extern "C" __global__ void prep_gbs_k(const float* __restrict__ emb,
                                      const float* __restrict__ pw,
                                      float* __restrict__ gbs) {
    int i = blockIdx.x * 256 + threadIdx.x;      // 8*768
    if (i >= 8 * 768) return;
    int b = i / 768, o = i - b * 768;
    const float* e = emb + b * 512;
    const float* wr = pw + o * 512;
    float s = 0.f;
    for (int k = 0; k < 512; k += 4) {
        float4 ev = *(const float4*)(e + k);
        float4 wv = *(const float4*)(wr + k);
        s += ev.x * wv.x + ev.y * wv.y + ev.z * wv.z + ev.w * wv.w;
    }
    gbs[i] = s;
}

extern "C" __global__ void prep_w_k(const float* __restrict__ wq, const float* __restrict__ wk,
                                    const float* __restrict__ wv, const float* __restrict__ wo,
                                    unsigned short* __restrict__ dst) {
    int i = blockIdx.x * 256 + threadIdx.x;      // 65536 float4-quads total
    int sel = i >> 14;
    const float* s = (sel == 0) ? wq : (sel == 1) ? wk : (sel == 2) ? wv : wo;
    float4 v = *(const float4*)(s + (i & 16383) * 4);
    ushort4 p;
    p.x = f2bf(v.x); p.y = f2bf(v.y); p.z = f2bf(v.z); p.w = f2bf(v.w);
    *(ushort4*)(dst + i * 4) = p;
}

extern "C" __global__ void prep_bias_k(const float* __restrict__ bt, float* __restrict__ bp) {
    int i = blockIdx.x * 256 + threadIdx.x;      // 8*64*64  [h][i][j]
    int h = i >> 12, r = (i >> 6) & 63, cc = i & 63;
    float v;
    if (cc >= 49) v = -1e30f;                    // mask pad key columns
    else if (r >= 49) v = 0.f;                   // dead query rows
    else {
        int ri = r / 7, ci = r - ri * 7, rj = cc / 7, cj = cc - rj * 7;
        int rel = (ri - rj + 6) * 13 + (ci - cj + 6);
        v = bt[rel * 8 + h];
    }
    bp[i] = v;
}

// ---------------- main fused kernel ----------------
// grid 2048, 512 threads (8 waves, wave w = head w). 51.2 KiB LDS -> 2 blocks/CU
// (r5's 76.8K left only 6K margin at 2x and did NOT fit: occupancy stayed 23%).
// Q, V, P live in registers (wave-private); only xm / K / attn-out touch LDS.
//   [0,25600)      xm  bf16 [50][256]  -> attn-out after bar2
//   [25600,51200)  k   bf16 [50][256]  (wave-private columns; no barrier needed)
// NOTE: __launch_bounds__ arg2 empirically acts as min BLOCKS/CU on this hipcc
// ((512,4) -> 64-VGPR cap -> catastrophic spill, r4). (512,2) -> 128-VGPR cap.
extern "C" __global__ void __launch_bounds__(512, 2)
attn_main(const float* __restrict__ x,
          const float* __restrict__ lnw, const float* __restrict__ lnb,
          const unsigned short* __restrict__ wqb, const unsigned short* __restrict__ wkb,
          const unsigned short* __restrict__ wvb, const unsigned short* __restrict__ wob,
          const float* __restrict__ gbs, const float* __restrict__ bpad,
          float* __restrict__ out)
{
    __shared__ char lds[51200];
    const int tid = threadIdx.x;
    const int w = tid >> 6;          // wave == head
    const int l = tid & 63;
    const int g = l >> 4;
    const int c = l & 15;
    const int win = blockIdx.x;
    const int bb = win >> 8;
    const int KR = 25600;
    const f32x4 z4 = {0.f, 0.f, 0.f, 0.f};
    const bf16x8 z8 = {0, 0, 0, 0, 0, 0, 0, 0};
    // shuffle-redistribution lanes (same for Q, V, P — validated in r4/r5)
    const int srcA = ((l >> 4) & 1) * 32 + (l & 15);
    const int srcB = srcA + 16;
    const bool hi2 = (g >= 2);       // selects dt' = g>>1 for Q/V
    const bool hiSel = (l >= 32);    // P's half-select

    // ---- AdaLayerNorm -> xm rows 0..48 (+ zero row 49) ----
    {
        float4 lnw4 = *(const float4*)(lnw + 4 * l);
        float4 lnb4 = *(const float4*)(lnb + 4 * l);
        float4 gam4 = *(const float4*)(gbs + bb * 768 + 4 * l);
        float4 bet4 = *(const float4*)(gbs + bb * 768 + 256 + 4 * l);
        for (int t = w; t < 49; t += 8) {
            float4 v = *(const float4*)(x + ((size_t)win * 49 + t) * 256 + 4 * l);
            float s = v.x + v.y + v.z + v.w;
            float ss = v.x * v.x + v.y * v.y + v.z * v.z + v.w * v.w;
            #pragma unroll
            for (int off = 32; off >= 1; off >>= 1) {
                s += __shfl_xor(s, off);
                ss += __shfl_xor(ss, off);
            }
            float mu = s * (1.0f / 256.0f);
            float var = ss * (1.0f / 256.0f) - mu * mu;
            float rstd = rsqrtf(var + 1e-5f);
            ushort4 p;
            p.x = f2bf(((v.x - mu) * rstd * lnw4.x + lnb4.x) * (1.0f + gam4.x) + bet4.x);
            p.y = f2bf(((v.y - mu) * rstd * lnw4.y + lnb4.y) * (1.0f + gam4.y) + bet4.y);
            p.z = f2bf(((v.z - mu) * rstd * lnw4.z + lnb4.z) * (1.0f + gam4.z) + bet4.z);
            p.w = f2bf(((v.w - mu) * rstd * lnw4.w + lnb4.w) * (1.0f + gam4.w) + bet4.w);
            *(ushort4*)(lds + swzA(t, 4 * l)) = p;
        }
        if (w == 7) {
            ushort4 zp; zp.x = 0; zp.y = 0; zp.z = 0; zp.w = 0;
            *(ushort4*)(lds + swzA(49, 4 * l)) = zp;
        }
    }
    __syncthreads();     // bar1: xm ready

    // ---- Q projection (swapped) -> registers via shuffle redistribution ----
    // acc[dt][tt][r] = Q[tok=tt*16+c][d = w*32 + dt*16 + 4g + r]
    // qf[it] element e = Q[it*16+c][w*32 + g*8 + e]
    bf16x8 qf[4];
    {
        f32x4 acc[2][4];
        #pragma unroll
        for (int dt = 0; dt < 2; ++dt)
            #pragma unroll
            for (int tt = 0; tt < 4; ++tt) acc[dt][tt] = z4;
        #pragma unroll
        for (int kt = 0; kt < 8; ++kt) {
            const int ko = kt * 32 + g * 8;
            bf16x8 b0 = *(const bf16x8*)(lds + swzA(c, ko));
            bf16x8 b1 = *(const bf16x8*)(lds + swzA(16 + c, ko));
            bf16x8 b2 = *(const bf16x8*)(lds + swzA(32 + c, ko));
            bf16x8 b3 = z8; if (c < 2) b3 = *(const bf16x8*)(lds + swzA(48 + c, ko));
            bf16x8 a0 = *(const bf16x8*)(wqb + (w * 32 + c) * 256 + ko);
            bf16x8 a1 = *(const bf16x8*)(wqb + (w * 32 + 16 + c) * 256 + ko);
            acc[0][0] = __builtin_amdgcn_mfma_f32_16x16x32_bf16(a0, b0, acc[0][0], 0, 0, 0);
            acc[0][1] = __builtin_amdgcn_mfma_f32_16x16x32_bf16(a0, b1, acc[0][1], 0, 0, 0);
            acc[0][2] = __builtin_amdgcn_mfma_f32_16x16x32_bf16(a0, b2, acc[0][2], 0, 0, 0);
            acc[0][3] = __builtin_amdgcn_mfma_f32_16x16x32_bf16(a0, b3, acc[0][3], 0, 0, 0);
            acc[1][0] = __builtin_amdgcn_mfma_f32_16x16x32_bf16(a1, b0, acc[1][0], 0, 0, 0);
            acc[1][1] = __builtin_amdgcn_mfma_f32_16x16x32_bf16(a1, b1, acc[1][1], 0, 0, 0);
            acc[1][2] = __builtin_amdgcn_mfma_f32_16x16x32_bf16(a1, b2, acc[1][2], 0, 0, 0);
            acc[1][3] = __builtin_amdgcn_mfma_f32_16x16x32_bf16(a1, b3, acc[1][3], 0, 0, 0);
        }
        unsigned qA[2][4], qB[2][4];
        #pragma unroll
        for (int dt = 0; dt < 2; ++dt)
            #pragma unroll
            for (int tt = 0; tt < 4; ++tt) {
                qA[dt][tt] = pack2(acc[dt][tt][0], acc[dt][tt][1]);
                qB[dt][tt] = pack2(acc[dt][tt][2], acc[dt][tt][3]);
            }
        #pragma unroll
        for (int it = 0; it < 4; ++it) {
            unsigned a0 = (unsigned)__shfl((int)qA[0][it], srcA);
            unsigned a1 = (unsigned)__shfl((int)qA[1][it], srcA);
            unsigned b0 = (unsigned)__shfl((int)qB[0][it], srcA);
            unsigned b1 = (unsigned)__shfl((int)qB[1][it], srcA);
            unsigned c0 = (unsigned)__shfl((int)qA[0][it], srcB);
            unsigned c1 = (unsigned)__shfl((int)qA[1][it], srcB);
            unsigned d0 = (unsigned)__shfl((int)qB[0][it], srcB);
            unsigned d1 = (unsigned)__shfl((int)qB[1][it], srcB);
            qf[it] = build8(hi2 ? a1 : a0, hi2 ? b1 : b0, hi2 ? c1 : c0, hi2 ? d1 : d0);
        }
    }

    // ---- K projection (swapped) -> LDS (wave-private columns) ----
    {
        f32x4 acc[2][4];
        #pragma unroll
        for (int dt = 0; dt < 2; ++dt)
            #pragma unroll
            for (int tt = 0; tt < 4; ++tt) acc[dt][tt] = z4;
        #pragma unroll
        for (int kt = 0; kt < 8; ++kt) {
            const int ko = kt * 32 + g * 8;
            bf16x8 b0 = *(const bf16x8*)(lds + swzA(c, ko));
            bf16x8 b1 = *(const bf16x8*)(lds + swzA(16 + c, ko));
            bf16x8 b2 = *(const bf16x8*)(lds + swzA(32 + c, ko));
            bf16x8 b3 = z8; if (c < 2) b3 = *(const bf16x8*)(lds + swzA(48 + c, ko));
            bf16x8 a0 = *(const bf16x8*)(wkb + (w * 32 + c) * 256 + ko);
            bf16x8 a1 = *(const bf16x8*)(wkb + (w * 32 + 16 + c) * 256 + ko);
            acc[0][0] = __builtin_amdgcn_mfma_f32_16x16x32_bf16(a0, b0, acc[0][0], 0, 0, 0);
            acc[0][1] = __builtin_amdgcn_mfma_f32_16x16x32_bf16(a0, b1, acc[0][1], 0, 0, 0);
            acc[0][2] = __builtin_amdgcn_mfma_f32_16x16x32_bf16(a0, b2, acc[0][2], 0, 0, 0);
            acc[0][3] = __builtin_amdgcn_mfma_f32_16x16x32_bf16(a0, b3, acc[0][3], 0, 0, 0);
            acc[1][0] = __builtin_amdgcn_mfma_f32_16x16x32_bf16(a1, b0, acc[1][0], 0, 0, 0);
            acc[1][1] = __builtin_amdgcn_mfma_f32_16x16x32_bf16(a1, b1, acc[1][1], 0, 0, 0);
            acc[1][2] = __builtin_amdgcn_mfma_f32_16x16x32_bf16(a1, b2, acc[1][2], 0, 0, 0);
            acc[1][3] = __builtin_amdgcn_mfma_f32_16x16x32_bf16(a1, b3, acc[1][3], 0, 0, 0);
        }
        #pragma unroll
        for (int dt = 0; dt < 2; ++dt)
            #pragma unroll
            for (int tt = 0; tt < 4; ++tt)
                if (tt < 3 || c < 2) {
                    uint2 u;
                    u.x = pack2(acc[dt][tt][0], acc[dt][tt][1]);
                    u.y = pack2(acc[dt][tt][2], acc[dt][tt][3]);
                    *(uint2*)(lds + KR + swzA(tt * 16 + c, w * 32 + dt * 16 + 4 * g)) = u;
                }
    }

    // ---- QK^T (swapped: sim^T) + softmax + fused in-reg P redistribution ----
    bf16x8 pv[4][2];
    {
        const int hd = w * 32 + g * 8;
        bf16x8 kf0 = *(const bf16x8*)(lds + KR + swzA(c, hd));
        bf16x8 kf1 = *(const bf16x8*)(lds + KR + swzA(16 + c, hd));
        bf16x8 kf2 = *(const bf16x8*)(lds + KR + swzA(32 + c, hd));
        bf16x8 kf3 = z8; if (c < 2) kf3 = *(const bf16x8*)(lds + KR + swzA(48 + c, hd));
        #pragma unroll
        for (int it = 0; it < 4; ++it) {
            f32x4 s0 = __builtin_amdgcn_mfma_f32_16x16x32_bf16(kf0, qf[it], z4, 0, 0, 0);
            f32x4 s1 = __builtin_amdgcn_mfma_f32_16x16x32_bf16(kf1, qf[it], z4, 0, 0, 0);
            f32x4 s2 = __builtin_amdgcn_mfma_f32_16x16x32_bf16(kf2, qf[it], z4, 0, 0, 0);
            f32x4 s3 = __builtin_amdgcn_mfma_f32_16x16x32_bf16(kf3, qf[it], z4, 0, 0, 0);
            const float* bp = bpad + w * 4096 + (it * 16 + c) * 64 + 4 * g;
            float4 B0 = *(const float4*)(bp);
            float4 B1 = *(const float4*)(bp + 16);
            float4 B2 = *(const float4*)(bp + 32);
            float4 B3 = *(const float4*)(bp + 48);
            s0[0] = s0[0] * SCALE_F + B0.x; s0[1] = s0[1] * SCALE_F + B0.y;
            s0[2] = s0[2] * SCALE_F + B0.z; s0[3] = s0[3] * SCALE_F + B0.w;
            s1[0] = s1[0] * SCALE_F + B1.x; s1[1] = s1[1] * SCALE_F + B1.y;
            s1[2] = s1[2] * SCALE_F + B1.z; s1[3] = s1[3] * SCALE_F + B1.w;
            s2[0] = s2[0] * SCALE_F + B2.x; s2[1] = s2[1] * SCALE_F + B2.y;
            s2[2] = s2[2] * SCALE_F + B2.z; s2[3] = s2[3] * SCALE_F + B2.w;
            s3[0] = s3[0] * SCALE_F + B3.x; s3[1] = s3[1] * SCALE_F + B3.y;
            s3[2] = s3[2] * SCALE_F + B3.z; s3[3] = s3[3] * SCALE_F + B3.w;
            float mm = fmaxf(fmaxf(fmaxf(s0[0], s0[1]), fmaxf(s0[2], s0[3])),
                       fmaxf(fmaxf(fmaxf(s1[0], s1[1]), fmaxf(s1[2], s1[3])),
                       fmaxf(fmaxf(fmaxf(s2[0], s2[1]), fmaxf(s2[2], s2[3])),
                             fmaxf(fmaxf(s3[0], s3[1]), fmaxf(s3[2], s3[3])))));
            mm = fmaxf(mm, __shfl_xor(mm, 16));
            mm = fmaxf(mm, __shfl_xor(mm, 32));
            #pragma unroll
            for (int r = 0; r < 4; ++r) {
                s0[r] = exp2f((s0[r] - mm) * LOG2E_F);
                s1[r] = exp2f((s1[r] - mm) * LOG2E_F);
                s2[r] = exp2f((s2[r] - mm) * LOG2E_F);
                s3[r] = exp2f((s3[r] - mm) * LOG2E_F);
            }
            float ss = (s0[0] + s0[1] + s0[2] + s0[3]) + (s1[0] + s1[1] + s1[2] + s1[3])
                     + (s2[0] + s2[1] + s2[2] + s2[3]) + (s3[0] + s3[1] + s3[2] + s3[3]);
            ss += __shfl_xor(ss, 16);
            ss += __shfl_xor(ss, 32);
            float iv = 1.0f / ss;
            #pragma unroll
            for (int r = 0; r < 4; ++r) { s0[r] *= iv; s1[r] *= iv; s2[r] *= iv; s3[r] *= iv; }
            unsigned pkt[4][2];
            pkt[0][0] = pack2(s0[0], s0[1]); pkt[0][1] = pack2(s0[2], s0[3]);
            pkt[1][0] = pack2(s1[0], s1[1]); pkt[1][1] = pack2(s1[2], s1[3]);
            pkt[2][0] = pack2(s2[0], s2[1]); pkt[2][1] = pack2(s2[2], s2[3]);
            pkt[3][0] = pack2(s3[0], s3[1]); pkt[3][1] = pack2(s3[2], s3[3]);
            #pragma unroll
            for (int kt = 0; kt < 2; ++kt) {
                unsigned x0, x1, u0, u1, u2, u3;
                x0 = (unsigned)__shfl((int)pkt[2 * kt][0], srcA);
                x1 = (unsigned)__shfl((int)pkt[2 * kt + 1][0], srcA);
                u0 = hiSel ? x1 : x0;
                x0 = (unsigned)__shfl((int)pkt[2 * kt][1], srcA);
                x1 = (unsigned)__shfl((int)pkt[2 * kt + 1][1], srcA);
                u1 = hiSel ? x1 : x0;
                x0 = (unsigned)__shfl((int)pkt[2 * kt][0], srcB);
                x1 = (unsigned)__shfl((int)pkt[2 * kt + 1][0], srcB);
                u2 = hiSel ? x1 : x0;
                x0 = (unsigned)__shfl((int)pkt[2 * kt][1], srcB);
                x1 = (unsigned)__shfl((int)pkt[2 * kt + 1][1], srcB);
                u3 = hiSel ? x1 : x0;
                pv[it][kt] = build8(u0, u1, u2, u3);
            }
        }
    }

    // ---- V projection (unswapped) -> registers via shuffle redistribution ----
    // acc[cti][tt][r] = V[tok = tt*16+4g+r][d = w*32 + cti*16 + c]
    // va[dt][kt] element e = V[tok = kt*32 + g*8 + e][d = w*32 + dt*16 + c]
    bf16x8 va[2][2];
    {
        f32x4 acc[2][4];
        #pragma unroll
        for (int cti = 0; cti < 2; ++cti)
            #pragma unroll
            for (int tt = 0; tt < 4; ++tt) acc[cti][tt] = z4;
        #pragma unroll
        for (int kt = 0; kt < 8; ++kt) {
            const int ko = kt * 32 + g * 8;
            bf16x8 a0 = *(const bf16x8*)(lds + swzA(c, ko));
            bf16x8 a1 = *(const bf16x8*)(lds + swzA(16 + c, ko));
            bf16x8 a2 = *(const bf16x8*)(lds + swzA(32 + c, ko));
            bf16x8 a3 = z8; if (c < 2) a3 = *(const bf16x8*)(lds + swzA(48 + c, ko));
            bf16x8 b0 = *(const bf16x8*)(wvb + (w * 32 + c) * 256 + ko);
            bf16x8 b1 = *(const bf16x8*)(wvb + (w * 32 + 16 + c) * 256 + ko);
            acc[0][0] = __builtin_amdgcn_mfma_f32_16x16x32_bf16(a0, b0, acc[0][0], 0, 0, 0);
            acc[0][1] = __builtin_amdgcn_mfma_f32_16x16x32_bf16(a1, b0, acc[0][1], 0, 0, 0);
            acc[0][2] = __builtin_amdgcn_mfma_f32_16x16x32_bf16(a2, b0, acc[0][2], 0, 0, 0);
            acc[0][3] = __builtin_amdgcn_mfma_f32_16x16x32_bf16(a3, b0, acc[0][3], 0, 0, 0);
            acc[1][0] = __builtin_amdgcn_mfma_f32_16x16x32_bf16(a0, b1, acc[1][0], 0, 0, 0);
            acc[1][1] = __builtin_amdgcn_mfma_f32_16x16x32_bf16(a1, b1, acc[1][1], 0, 0, 0);
            acc[1][2] = __builtin_amdgcn_mfma_f32_16x16x32_bf16(a2, b1, acc[1][2], 0, 0, 0);
            acc[1][3] = __builtin_amdgcn_mfma_f32_16x16x32_bf16(a3, b1, acc[1][3], 0, 0, 0);
        }
        unsigned vA[2][4], vB[2][4];
        #pragma unroll
        for (int cti = 0; cti < 2; ++cti)
            #pragma unroll
            for (int tt = 0; tt < 4; ++tt) {
                vA[cti][tt] = pack2(acc[cti][tt][0], acc[cti][tt][1]);
                vB[cti][tt] = pack2(acc[cti][tt][2], acc[cti][tt][3]);
            }
        #pragma unroll
        for (int dt = 0; dt < 2; ++dt)
            #pragma unroll
            for (int kt = 0; kt < 2; ++kt) {
                unsigned a0 = (unsigned)__shfl((int)vA[dt][2 * kt],     srcA);
                unsigned a1 = (unsigned)__shfl((int)vA[dt][2 * kt + 1], srcA);
                unsigned b0 = (unsigned)__shfl((int)vB[dt][2 * kt],     srcA);
                unsigned b1 = (unsigned)__shfl((int)vB[dt][2 * kt + 1], srcA);
                unsigned c0 = (unsigned)__shfl((int)vA[dt][2 * kt],     srcB);
                unsigned c1 = (unsigned)__shfl((int)vA[dt][2 * kt + 1], srcB);
                unsigned d0 = (unsigned)__shfl((int)vB[dt][2 * kt],     srcB);
                unsigned d1 = (unsigned)__shfl((int)vB[dt][2 * kt + 1], srcB);
                va[dt][kt] = build8(hi2 ? a1 : a0, hi2 ? b1 : b0, hi2 ? c1 : c0, hi2 ? d1 : d0);
            }
    }
    __syncthreads();     // bar2: all xm reads done -> attn-out may overwrite xm

    // ---- PV (A = va regs, B = pv regs) -> attn-out[tok][d] into xm region ----
    {
        f32x4 o[2][4];   // [dt][it]
        #pragma unroll
        for (int dt = 0; dt < 2; ++dt)
            #pragma unroll
            for (int it = 0; it < 4; ++it) o[dt][it] = z4;
        #pragma unroll
        for (int kt = 0; kt < 2; ++kt)
            #pragma unroll
            for (int it = 0; it < 4; ++it) {
                o[0][it] = __builtin_amdgcn_mfma_f32_16x16x32_bf16(va[0][kt], pv[it][kt], o[0][it], 0, 0, 0);
                o[1][it] = __builtin_amdgcn_mfma_f32_16x16x32_bf16(va[1][kt], pv[it][kt], o[1][it], 0, 0, 0);
            }
        #pragma unroll
        for (int dt = 0; dt < 2; ++dt)
            #pragma unroll
            for (int it = 0; it < 4; ++it)
                if (it < 3 || c < 2) {
                    uint2 u;
                    u.x = pack2(o[dt][it][0], o[dt][it][1]);
                    u.y = pack2(o[dt][it][2], o[dt][it][3]);
                    *(uint2*)(lds + swzA(it * 16 + c, w * 32 + dt * 16 + 4 * g)) = u;
                }
    }
    __syncthreads();     // bar3: attn-out ready

    // ---- O projection (swapped) + sigma gate -> float4 global stores ----
    {
        f32x4 acc[2][4];
        #pragma unroll
        for (int dt = 0; dt < 2; ++dt)
            #pragma unroll
            for (int tt = 0; tt < 4; ++tt) acc[dt][tt] = z4;
        #pragma unroll
        for (int kt = 0; kt < 8; ++kt) {
            const int ko = kt * 32 + g * 8;
            bf16x8 b0 = *(const bf16x8*)(lds + swzA(c, ko));
            bf16x8 b1 = *(const bf16x8*)(lds + swzA(16 + c, ko));
            bf16x8 b2 = *(const bf16x8*)(lds + swzA(32 + c, ko));
            bf16x8 b3 = z8; if (c < 2) b3 = *(const bf16x8*)(lds + swzA(48 + c, ko));
            bf16x8 a0 = *(const bf16x8*)(wob + (w * 32 + c) * 256 + ko);
            bf16x8 a1 = *(const bf16x8*)(wob + (w * 32 + 16 + c) * 256 + ko);
            acc[0][0] = __builtin_amdgcn_mfma_f32_16x16x32_bf16(a0, b0, acc[0][0], 0, 0, 0);
            acc[0][1] = __builtin_amdgcn_mfma_f32_16x16x32_bf16(a0, b1, acc[0][1], 0, 0, 0);
            acc[0][2] = __builtin_amdgcn_mfma_f32_16x16x32_bf16(a0, b2, acc[0][2], 0, 0, 0);
            acc[0][3] = __builtin_amdgcn_mfma_f32_16x16x32_bf16(a0, b3, acc[0][3], 0, 0, 0);
            acc[1][0] = __builtin_amdgcn_mfma_f32_16x16x32_bf16(a1, b0, acc[1][0], 0, 0, 0);
            acc[1][1] = __builtin_amdgcn_mfma_f32_16x16x32_bf16(a1, b1, acc[1][1], 0, 0, 0);
            acc[1][2] = __builtin_amdgcn_mfma_f32_16x16x32_bf16(a1, b2, acc[1][2], 0, 0, 0);
            acc[1][3] = __builtin_amdgcn_mfma_f32_16x16x32_bf16(a1, b3, acc[1][3], 0, 0, 0);
        }
        #pragma unroll
        for (int dt = 0; dt < 2; ++dt) {
            const int col = w * 32 + dt * 16 + 4 * g;
            float4 sg = *(const float4*)(gbs + bb * 768 + 512 + col);
            #pragma unroll
            for (int tt = 0; tt < 4; ++tt) {
                int tok = tt * 16 + c;
                if (tok < 49) {
                    float4 o4;
                    o4.x = acc[dt][tt][0] * sg.x;
                    o4.y = acc[dt][tt][1] * sg.y;
                    o4.z = acc[dt][tt][2] * sg.z;
                    o4.w = acc[dt][tt][3] * sg.w;
                    *(float4*)(out + ((size_t)win * 49 + tok) * 256 + col) = o4;
                }
            }
        }
    }
}

extern "C" void kernel_launch(void* const* d_in, const int* in_sizes, int n_in,
                              void* d_out, int out_size, void* d_ws, size_t ws_size,
                              hipStream_t stream) {
    (void)in_sizes; (void)n_in; (void)out_size; (void)ws_size;
    const float* x   = (const float*)d_in[0];
    const float* emb = (const float*)d_in[1];
    const float* lnw = (const float*)d_in[2];
    const float* lnb = (const float*)d_in[3];
    const float* pw  = (const float*)d_in[4];
    const float* wq  = (const float*)d_in[5];
    const float* wk  = (const float*)d_in[6];
    const float* wv  = (const float*)d_in[7];
    const float* wo  = (const float*)d_in[8];
    const float* bt  = (const float*)d_in[9];
    float* out = (float*)d_out;

    char* ws = (char*)d_ws;
    float* gbs = (float*)ws;                                   // 24576 B
    unsigned short* wb = (unsigned short*)(ws + 24576);        // 524288 B
    float* biasp = (float*)(ws + 24576 + 524288);              // 131072 B

    prep_gbs_k<<<24, 256, 0, stream>>>(emb, pw, gbs);
    prep_w_k<<<256, 256, 0, stream>>>(wq, wk, wv, wo, wb);
    prep_bias_k<<<128, 256, 0, stream>>>(bt, biasp);
    attn_main<<<2048, 512, 0, stream>>>(x, lnw, lnb,
                                        wb, wb + 65536, wb + 131072, wb + 196608,
                                        gbs, biasp, out);
}